// Round 7
// baseline (577.773 us; speedup 1.0000x reference)
//
#include <hip/hip_runtime.h>

// GradientConsistencyLoss on f[2,3,192,192,192] fp32.
// loss = 0.1 * ( mean(div^2) + mean(sqrt(cx^2+cy^2+cz^2+1e-8)) )
// jnp.gradient semantics: central interior, one-sided edges, unit spacing.
//
// R7: LDS plane-staging, spill-trap-free. Evidence: R1..R6 are all bound by
// per-CU outstanding-miss-rate (no pipe >50%); levers = fewer issued lines +
// longer issue->use slack. R4 proved the concept but spilled 208 MB because
// halo registers lived across iterations under divergent guards. Here:
//  - loop-carried regs (prev/cur/nxt centers) are uniform-control only
//  - halo loads are iteration-local: load at top, LDS-store at bottom
//  - per step/thread: 3 center ld4 (plane d+2, consumed 2 rotations later)
//    + ~0.75 halo loads; h/w neighbors from double-buffered LDS plane
//  - LDS 30 KB, row stride 68 floats (16B-aligned for b128, spreads banks)

#define DEP 192
#define HGT 192
#define WID 192
#define NB  2

constexpr int SD = HGT * WID;            // d-stride (floats)
constexpr int SC = DEP * SD;             // channel stride
constexpr int SB = 3 * SC;               // batch stride
constexpr int TH  = 16;                  // tile rows (h)
constexpr int TW4 = 16;                  // tile float4-cols
constexpr int TW  = TW4 * 4;             // 64 floats of w
constexpr int DSEG = 12;                 // planes per block
constexpr int NDS = DEP / DSEG;          // 16
constexpr int NHB = HGT / TH;            // 12
constexpr int NWB = WID / TW;            // 3
constexpr int NBLK = NB * NDS * NHB * NWB;   // 1152 blocks
constexpr int ROWF = TW + 4;             // 68: 16B-aligned rows, bank spread
constexpr float SCALE = (float)(0.1 / (double)((long long)NB * DEP * HGT * WID));
constexpr float EPS_C = 1e-8f;

struct V4 { float v[4]; };
__device__ __forceinline__ V4 ld4(const float* p) {
    const float4 t = *(const float4*)p;
    V4 r; r.v[0] = t.x; r.v[1] = t.y; r.v[2] = t.z; r.v[3] = t.w; return r;
}
__device__ __forceinline__ void st4(float* p, const V4& a) {
    *(float4*)p = make_float4(a.v[0], a.v[1], a.v[2], a.v[3]);
}

__global__ __launch_bounds__(256, 4) void gcl_kernel(const float* __restrict__ f,
                                                     float* __restrict__ ws) {
    // [dbuf][ch][row: 0=top halo, 1..16 centers, 17=bot halo][w + pad]
    __shared__ float buf[2][3][TH + 2][ROWF];
    __shared__ float wcol[2][3][TH][2];          // [dbuf][ch][row][L/R]

    const int tid = threadIdx.x;
    const int tx = tid & 15;
    const int ty = tid >> 4;

    int bid = blockIdx.x;
    const int wb = bid % NWB; bid /= NWB;
    const int hb = bid % NHB; bid /= NHB;
    const int dsg = bid % NDS;
    const int b = bid / NDS;

    const int h0 = hb * TH, w0 = wb * TW, d0 = dsg * DSEG;
    const int h = h0 + ty;
    const int w = w0 + tx * 4;

    const float sy  = (h == 0 || h == HGT - 1) ? 1.0f : 0.5f;
    const float s0w = (w == 0) ? 1.0f : 0.5f;
    const float s3w = (w + 3 == WID - 1) ? 1.0f : 0.5f;

    const float* fb = f + b * SB;
    const float* basec = fb + h * WID + w;       // + c*SC + d*SD

    // halo roles: tid<96 -> h-halo rows [ch(3)][side(2)][tx(16)]
    const int  hch  = tid >> 5;                  // valid for tid<96
    const bool hTop = ((tid >> 4) & 1) == 0;
    const int  htx  = tid & 15;
    const int  hrow = hTop ? (h0 > 0 ? h0 - 1 : 0)
                           : (h0 + TH < HGT ? h0 + TH : HGT - 1);
    const int  hldsrow = hTop ? 0 : TH + 1;
    // tid in [96,192) -> w-halo cols [ch(3)][side(2)][row(16)]
    const int  cq   = tid - 96;
    const int  cch  = cq >> 5;
    const bool cLft = ((cq >> 4) & 1) == 0;
    const int  crow = cq & 15;
    const int  ccol = cLft ? (w0 > 0 ? w0 - 1 : 0)
                           : (w0 + TW < WID ? w0 + TW : WID - 1);

    // rolling d-pipeline: centers only (uniform control, loop-carried)
    V4 prev[3], cur[3], nxt[3];
    const int pm = (d0 > 0) ? d0 - 1 : 0;
#pragma unroll
    for (int c = 0; c < 3; ++c) {
        prev[c] = ld4(basec + c * SC + pm * SD);
        cur[c]  = ld4(basec + c * SC + d0 * SD);
        nxt[c]  = ld4(basec + c * SC + (d0 + 1) * SD);  // d0+1 <= 181
    }
    // stage plane d0 into buf[0]
#pragma unroll
    for (int c = 0; c < 3; ++c)
        st4(&buf[0][c][ty + 1][tx * 4], cur[c]);
    if (tid < 96) {
        const V4 hv = ld4(fb + hch * SC + d0 * SD + hrow * WID + w0 + htx * 4);
        st4(&buf[0][hch][hldsrow][htx * 4], hv);
    } else if (tid < 192) {
        wcol[0][cch][crow][cLft ? 0 : 1] =
            fb[cch * SC + d0 * SD + (h0 + crow) * WID + ccol];
    }
    __syncthreads();

    float local = 0.f;

#pragma unroll
    for (int s = 0; s < DSEG; ++s) {
        const int d = d0 + s;
        const int pb = s & 1, qb = pb ^ 1;

        // ---- staging for plane d+1 / prefetch d+2 (iteration-local) ----
        V4 nn[3];
        V4 hv = {};
        float cv = 0.f;
        if (s < DSEG - 1) {
            const int d2 = (d + 2 < DEP) ? d + 2 : DEP - 1;  // clamp == edge rule
#pragma unroll
            for (int c = 0; c < 3; ++c)
                nn[c] = ld4(basec + c * SC + d2 * SD);
            if (tid < 96)
                hv = ld4(fb + hch * SC + (d + 1) * SD + hrow * WID + w0 + htx * 4);
            else if (tid < 192)
                cv = fb[cch * SC + (d + 1) * SD + (h0 + crow) * WID + ccol];
            // center rows of plane d+1 come straight from regs (no load)
#pragma unroll
            for (int c = 0; c < 3; ++c)
                st4(&buf[qb][c][ty + 1][tx * 4], nxt[c]);
        }

        // ---- compute plane d from buf[pb] + prev/cur/nxt ----
        const float sx = (d == 0 || d == DEP - 1) ? 1.0f : 0.5f;
        float dv[4], cx[4], cy[4], cz[4];
        {   // c = 0: gx->+div, gy->+cz, gz->-cy
            const V4 hm = ld4(&buf[pb][0][ty][tx * 4]);
            const V4 hp = ld4(&buf[pb][0][ty + 2][tx * 4]);
            const float lv = (tx == 0)  ? wcol[pb][0][ty][0] : buf[pb][0][ty + 1][tx * 4 - 1];
            const float rv = (tx == 15) ? wcol[pb][0][ty][1] : buf[pb][0][ty + 1][tx * 4 + 4];
#pragma unroll
            for (int j = 0; j < 4; ++j) {
                dv[j] = sx * (nxt[0].v[j] - prev[0].v[j]);
                cz[j] = sy * (hp.v[j] - hm.v[j]);
            }
            cy[0] = -(s0w * (cur[0].v[1] - lv));
            cy[1] = -(0.5f * (cur[0].v[2] - cur[0].v[0]));
            cy[2] = -(0.5f * (cur[0].v[3] - cur[0].v[1]));
            cy[3] = -(s3w * (rv - cur[0].v[2]));
        }
        {   // c = 1: gy->+div, gz->+cx, gx->-cz
            const V4 hm = ld4(&buf[pb][1][ty][tx * 4]);
            const V4 hp = ld4(&buf[pb][1][ty + 2][tx * 4]);
            const float lv = (tx == 0)  ? wcol[pb][1][ty][0] : buf[pb][1][ty + 1][tx * 4 - 1];
            const float rv = (tx == 15) ? wcol[pb][1][ty][1] : buf[pb][1][ty + 1][tx * 4 + 4];
#pragma unroll
            for (int j = 0; j < 4; ++j) {
                dv[j] += sy * (hp.v[j] - hm.v[j]);
                cz[j] -= sx * (nxt[1].v[j] - prev[1].v[j]);
            }
            cx[0] = s0w * (cur[1].v[1] - lv);
            cx[1] = 0.5f * (cur[1].v[2] - cur[1].v[0]);
            cx[2] = 0.5f * (cur[1].v[3] - cur[1].v[1]);
            cx[3] = s3w * (rv - cur[1].v[2]);
        }
        {   // c = 2: gz->+div, gy->-cx, gx->+cy
            const V4 hm = ld4(&buf[pb][2][ty][tx * 4]);
            const V4 hp = ld4(&buf[pb][2][ty + 2][tx * 4]);
            const float lv = (tx == 0)  ? wcol[pb][2][ty][0] : buf[pb][2][ty + 1][tx * 4 - 1];
            const float rv = (tx == 15) ? wcol[pb][2][ty][1] : buf[pb][2][ty + 1][tx * 4 + 4];
            dv[0] += s0w * (cur[2].v[1] - lv);
            dv[1] += 0.5f * (cur[2].v[2] - cur[2].v[0]);
            dv[2] += 0.5f * (cur[2].v[3] - cur[2].v[1]);
            dv[3] += s3w * (rv - cur[2].v[2]);
#pragma unroll
            for (int j = 0; j < 4; ++j) {
                cx[j] -= sy * (hp.v[j] - hm.v[j]);
                cy[j] += sx * (nxt[2].v[j] - prev[2].v[j]);
            }
        }
#pragma unroll
        for (int j = 0; j < 4; ++j)
            local += dv[j] * dv[j] +
                     __builtin_amdgcn_sqrtf(cx[j] * cx[j] + cy[j] * cy[j] +
                                            cz[j] * cz[j] + EPS_C);

        // ---- finish staging, barrier, rotate (all uniform control) ----
        if (s < DSEG - 1) {
            if (tid < 96)
                st4(&buf[qb][hch][hldsrow][htx * 4], hv);
            else if (tid < 192)
                wcol[qb][cch][crow][cLft ? 0 : 1] = cv;
            __syncthreads();
#pragma unroll
            for (int c = 0; c < 3; ++c) {
                prev[c] = cur[c]; cur[c] = nxt[c]; nxt[c] = nn[c];
            }
        }
    }

    // ---- wave64 butterfly -> cross-wave LDS -> one store per block ----
#pragma unroll
    for (int off = 32; off > 0; off >>= 1)
        local += __shfl_down(local, off, 64);

    __shared__ float wsum[4];
    const int lane = tid & 63;
    const int wv   = tid >> 6;
    if (lane == 0) wsum[wv] = local;
    __syncthreads();
    if (tid == 0)
        ws[blockIdx.x] = wsum[0] + wsum[1] + wsum[2] + wsum[3];
}

__global__ __launch_bounds__(256) void gcl_reduce(const float* __restrict__ ws,
                                                  float* __restrict__ out) {
    float s = 0.f;
    for (int i = threadIdx.x; i < NBLK; i += 256) s += ws[i];
#pragma unroll
    for (int off = 32; off > 0; off >>= 1)
        s += __shfl_down(s, off, 64);
    __shared__ float wsum[4];
    const int lane = threadIdx.x & 63;
    const int wv   = threadIdx.x >> 6;
    if (lane == 0) wsum[wv] = s;
    __syncthreads();
    if (threadIdx.x == 0)
        out[0] = (wsum[0] + wsum[1] + wsum[2] + wsum[3]) * SCALE;
}

extern "C" void kernel_launch(void* const* d_in, const int* in_sizes, int n_in,
                              void* d_out, int out_size, void* d_ws, size_t ws_size,
                              hipStream_t stream) {
    const float* f = (const float*)d_in[0];
    float* out = (float*)d_out;
    float* ws  = (float*)d_ws;   // NBLK*4 = 4.5 KB scratch
    gcl_kernel<<<dim3(NBLK), dim3(256), 0, stream>>>(f, ws);
    gcl_reduce<<<dim3(1), dim3(256), 0, stream>>>(ws, out);
}

// Round 8
// 233.979 us; speedup vs baseline: 2.4693x; 2.4693x over previous
//
#include <hip/hip_runtime.h>

// GradientConsistencyLoss on f[2,3,192,192,192] fp32.
// loss = 0.1 * ( mean(div^2) + mean(sqrt(cx^2+cy^2+cz^2+1e-8)) )
// jnp.gradient semantics: central interior, one-sided edges, unit spacing.
//
// R8: row-pair register tiling. Evidence: time tracks issued L1-level bytes
// (R2 17.3 B/cyc/CU, R3 14.2); LDS staging spills (R4/R7: compiler demotes
// to scratch). So cut issued bytes IN REGISTERS:
//  - wave = one w-row-pair: lane owns float3 (64*3 = 192 = full row), rows
//    (h,h+1); w-neighbors via __shfl (lane 0/63 = true edges, NO edge loads)
//  - gy uses the partner row's pipeline register: h-halo = 2 loads/pair/step
//  - d marches with R3's proven 1-iter-ahead prefetch (nn/nhm/nhp)
//  - per step: 12 float3 loads per 6 voxels = 24 B/voxel (R3: 42)
// All loop-carried state wave-uniform -> no scratch-demotion trigger.

#define DEP 192
#define HGT 192
#define WID 192
#define NB  2

constexpr int SD = HGT * WID;             // d-stride (floats)
constexpr int SC = DEP * SD;              // channel stride
constexpr int SB = 3 * SC;                // batch stride
constexpr int DSEG = 12;                  // planes per thread
constexpr int NSEG = DEP / DSEG;          // 16
constexpr int RPB  = 4;                   // row-pairs per block (= waves)
constexpr int NRPG = (HGT / 2) / RPB;     // 24 row-pair groups
constexpr int NBLK = NB * NSEG * NRPG;    // 768 blocks = 3/CU exactly
constexpr float SCALE = (float)(0.1 / (double)((long long)NB * DEP * HGT * WID));
constexpr float EPS_C = 1e-8f;

struct V3 { float x, y, z; };
__device__ __forceinline__ V3 ld3(const float* p) {
    const float3 t = *(const float3*)p;     // 12B load -> global_load_dwordx3
    V3 r; r.x = t.x; r.y = t.y; r.z = t.z; return r;
}

__global__ __launch_bounds__(256, 3) void gcl_kernel(const float* __restrict__ f,
                                                     float* __restrict__ ws) {
    const int tid  = threadIdx.x;
    const int lane = tid & 63;
    const int wv   = tid >> 6;

    int bid = blockIdx.x;
    const int rpg = bid % NRPG; bid /= NRPG;
    const int dsg = bid % NSEG;
    const int b   = bid / NSEG;

    const int h0 = (rpg * RPB + wv) * 2;      // even row of the pair
    const int h1 = h0 + 1;
    const int w  = lane * 3;
    const int d0 = dsg * DSEG;

    const int hmrow = (h0 > 0) ? h0 - 1 : 0;
    const int hprow = (h1 < HGT - 1) ? h1 + 1 : HGT - 1;
    const float sy0 = (h0 == 0) ? 1.f : 0.5f;
    const float sy1 = (h1 == HGT - 1) ? 1.f : 0.5f;
    const float s0w = (lane == 0) ? 1.f : 0.5f;   // w==0 true edge
    const float s2w = (lane == 63) ? 1.f : 0.5f;  // w+2==191 true edge

    const float* base = f + b * SB + w;
    const int r0 = h0 * WID, r1 = h1 * WID, rm = hmrow * WID, rp = hprow * WID;

    // rolling d-pipeline (all wave-uniform control)
    V3 prev[3][2], cur[3][2], nxt[3][2], hm[3], hp[3];
    const int pm = (d0 > 0) ? d0 - 1 : 0;
#pragma unroll
    for (int c = 0; c < 3; ++c) {
        const float* pc = base + c * SC;
        prev[c][0] = ld3(pc + pm * SD + r0);
        prev[c][1] = ld3(pc + pm * SD + r1);
        cur[c][0]  = ld3(pc + d0 * SD + r0);
        cur[c][1]  = ld3(pc + d0 * SD + r1);
        nxt[c][0]  = ld3(pc + (d0 + 1) * SD + r0);   // d0+1 <= 181
        nxt[c][1]  = ld3(pc + (d0 + 1) * SD + r1);
        hm[c]      = ld3(pc + d0 * SD + rm);
        hp[c]      = ld3(pc + d0 * SD + rp);
    }

    float local = 0.f;

#pragma unroll
    for (int s = 0; s < DSEG; ++s) {
        const int d = d0 + s;

        // ---- prefetch everything for step s+1 (one full iteration early) ----
        V3 nn[3][2], nhm[3], nhp[3];
        if (s < DSEG - 1) {
            const int dn = d + 1;
            const int d2 = (d + 2 < DEP) ? d + 2 : DEP - 1;  // clamp == edge rule
#pragma unroll
            for (int c = 0; c < 3; ++c) {
                const float* pc = base + c * SC;
                nn[c][0] = ld3(pc + d2 * SD + r0);
                nn[c][1] = ld3(pc + d2 * SD + r1);
                nhm[c]   = ld3(pc + dn * SD + rm);
                nhp[c]   = ld3(pc + dn * SD + rp);
            }
        }

        const float sx = (d == 0 || d == DEP - 1) ? 1.f : 0.5f;

#pragma unroll
        for (int r = 0; r < 2; ++r) {
            const float syr = r ? sy1 : sy0;
            float gx[3][3], gy[3][3], gz[3][3];
#pragma unroll
            for (int c = 0; c < 3; ++c) {
                // d-gradient from pipeline registers
                gx[c][0] = sx * (nxt[c][r].x - prev[c][r].x);
                gx[c][1] = sx * (nxt[c][r].y - prev[c][r].y);
                gx[c][2] = sx * (nxt[c][r].z - prev[c][r].z);
                // h-gradient: partner row is a register; halo rows loaded
                const V3 lo = r ? cur[c][0] : hm[c];
                const V3 hi = r ? hp[c]     : cur[c][1];
                gy[c][0] = syr * (hi.x - lo.x);
                gy[c][1] = syr * (hi.y - lo.y);
                gy[c][2] = syr * (hi.z - lo.z);
                // w-gradient: cross-lane shuffles, true edges at lane 0/63
                float lv = __shfl_up(cur[c][r].z, 1, 64);
                float rv = __shfl_down(cur[c][r].x, 1, 64);
                if (lane == 0)  lv = cur[c][r].x;
                if (lane == 63) rv = cur[c][r].z;
                gz[c][0] = s0w * (cur[c][r].y - lv);
                gz[c][1] = 0.5f * (cur[c][r].z - cur[c][r].x);
                gz[c][2] = s2w * (rv - cur[c][r].y);
            }
#pragma unroll
            for (int j = 0; j < 3; ++j) {
                const float dv = gx[0][j] + gy[1][j] + gz[2][j];
                const float cx = gz[1][j] - gy[2][j];
                const float cy = gx[2][j] - gz[0][j];
                const float cz = gy[0][j] - gx[1][j];
                local += dv * dv +
                         __builtin_amdgcn_sqrtf(cx * cx + cy * cy + cz * cz + EPS_C);
            }
        }

        // ---- rotate pipeline (uniform control) ----
        if (s < DSEG - 1) {
#pragma unroll
            for (int c = 0; c < 3; ++c) {
                prev[c][0] = cur[c][0]; prev[c][1] = cur[c][1];
                cur[c][0]  = nxt[c][0]; cur[c][1]  = nxt[c][1];
                nxt[c][0]  = nn[c][0];  nxt[c][1]  = nn[c][1];
                hm[c] = nhm[c]; hp[c] = nhp[c];
            }
        }
    }

    // ---- wave64 butterfly -> cross-wave LDS -> one store per block ----
#pragma unroll
    for (int off = 32; off > 0; off >>= 1)
        local += __shfl_down(local, off, 64);

    __shared__ float wsum[4];
    if (lane == 0) wsum[wv] = local;
    __syncthreads();
    if (tid == 0)
        ws[blockIdx.x] = wsum[0] + wsum[1] + wsum[2] + wsum[3];
}

__global__ __launch_bounds__(256) void gcl_reduce(const float* __restrict__ ws,
                                                  float* __restrict__ out) {
    float s = 0.f;
    for (int i = threadIdx.x; i < NBLK; i += 256) s += ws[i];
#pragma unroll
    for (int off = 32; off > 0; off >>= 1)
        s += __shfl_down(s, off, 64);
    __shared__ float wsum[4];
    const int lane = threadIdx.x & 63;
    const int wv   = threadIdx.x >> 6;
    if (lane == 0) wsum[wv] = s;
    __syncthreads();
    if (threadIdx.x == 0)
        out[0] = (wsum[0] + wsum[1] + wsum[2] + wsum[3]) * SCALE;
}

extern "C" void kernel_launch(void* const* d_in, const int* in_sizes, int n_in,
                              void* d_out, int out_size, void* d_ws, size_t ws_size,
                              hipStream_t stream) {
    const float* f = (const float*)d_in[0];
    float* out = (float*)d_out;
    float* ws  = (float*)d_ws;   // NBLK*4 = 3 KB scratch
    gcl_kernel<<<dim3(NBLK), dim3(256), 0, stream>>>(f, ws);
    gcl_reduce<<<dim3(1), dim3(256), 0, stream>>>(ws, out);
}